// Round 3
// baseline (118.076 us; speedup 1.0000x reference)
//
#include <hip/hip_runtime.h>

// NestedLoop: out = inp * prod_{i=0}^{7}(1 + 28*i) — pure streaming scale.
// R3: same as R2 but with clang ext_vector float4 so the nontemporal
// builtins compile (HIP_vector_type structs are rejected by the builtin).

typedef float v4f __attribute__((ext_vector_type(4)));

__global__ __launch_bounds__(256) void NestedLoop_29626684408030_kernel(
    const v4f* __restrict__ in, v4f* __restrict__ out, int n4) {
    // Constant-folded fp32 loop recurrence for the multiplier (matches the
    // reference's rounding path; all-constant -> folded at compile time).
    float s = 1.0f;
#pragma unroll
    for (int i = 0; i < 8; ++i) {
        float b = s * (float)i;
#pragma unroll
        for (int j = 0; j < 8; ++j) {
            s = s + b * (float)j;
        }
    }

    int tid = blockIdx.x * blockDim.x + threadIdx.x;
    int stride = gridDim.x * blockDim.x;

    int k = tid;
    // Main loop: 4 independent loads issued back-to-back, then 4 stores.
    for (; k + 3 * stride < n4; k += 4 * stride) {
        v4f v0 = __builtin_nontemporal_load(&in[k]);
        v4f v1 = __builtin_nontemporal_load(&in[k + stride]);
        v4f v2 = __builtin_nontemporal_load(&in[k + 2 * stride]);
        v4f v3 = __builtin_nontemporal_load(&in[k + 3 * stride]);
        v0 *= s; v1 *= s; v2 *= s; v3 *= s;
        __builtin_nontemporal_store(v0, &out[k]);
        __builtin_nontemporal_store(v1, &out[k + stride]);
        __builtin_nontemporal_store(v2, &out[k + 2 * stride]);
        __builtin_nontemporal_store(v3, &out[k + 3 * stride]);
    }
    // Tail (not taken for N=64M with this grid, but keep it correct).
    for (; k < n4; k += stride) {
        v4f v = __builtin_nontemporal_load(&in[k]);
        v *= s;
        __builtin_nontemporal_store(v, &out[k]);
    }
}

extern "C" void kernel_launch(void* const* d_in, const int* in_sizes, int n_in,
                              void* d_out, int out_size, void* d_ws, size_t ws_size,
                              hipStream_t stream) {
    const v4f* in = (const v4f*)d_in[0];
    v4f* out = (v4f*)d_out;
    int n = in_sizes[0];          // 67,108,864 floats
    int n4 = n / 4;               // 16,777,216 float4s

    const int block = 256;
    int grid = 2048;              // 256 CUs x 8 blocks/CU; 4-deep batches cover n4 in 8 sweeps
    NestedLoop_29626684408030_kernel<<<grid, block, 0, stream>>>(in, out, n4);
}

// Round 4
// 85.328 us; speedup vs baseline: 1.3838x; 1.3838x over previous
//
#include <hip/hip_runtime.h>

// NestedLoop: out = inp * prod_{i=0}^{7}(1 + 28*i) — pure streaming scale.
// R4: R1's simple grid-stride structure, but stores are NON-TEMPORAL ONLY
// (LLC no-allocate on writes). Input (256 MiB) exactly fits Infinity Cache;
// keeping output out of L3 lets the input stay resident across graph
// replays -> reads from L3, writes stream to HBM. Loads stay cacheable.

typedef float v4f __attribute__((ext_vector_type(4)));

__global__ __launch_bounds__(256) void NestedLoop_29626684408030_kernel(
    const v4f* __restrict__ in, v4f* __restrict__ out, int n4) {
    // Constant-folded fp32 loop recurrence for the multiplier (matches the
    // reference's rounding path; all-constant -> folded at compile time).
    float s = 1.0f;
#pragma unroll
    for (int i = 0; i < 8; ++i) {
        float b = s * (float)i;
#pragma unroll
        for (int j = 0; j < 8; ++j) {
            s = s + b * (float)j;
        }
    }

    int idx = blockIdx.x * blockDim.x + threadIdx.x;
    int stride = gridDim.x * blockDim.x;
    for (int k = idx; k < n4; k += stride) {
        v4f v = in[k];           // cacheable load — let L3 retain the input
        v *= s;
        __builtin_nontemporal_store(v, &out[k]);  // no-allocate store
    }
}

extern "C" void kernel_launch(void* const* d_in, const int* in_sizes, int n_in,
                              void* d_out, int out_size, void* d_ws, size_t ws_size,
                              hipStream_t stream) {
    const v4f* in = (const v4f*)d_in[0];
    v4f* out = (v4f*)d_out;
    int n = in_sizes[0];          // 67,108,864 floats
    int n4 = n / 4;               // 16,777,216 float4s

    const int block = 256;
    int grid = 2048;              // 256 CUs x 8 blocks/CU (32 waves/CU)
    NestedLoop_29626684408030_kernel<<<grid, block, 0, stream>>>(in, out, n4);
}